// Round 12
// baseline (883.967 us; speedup 1.0000x reference)
//
#include <hip/hip_runtime.h>
#include <hip/hip_bf16.h>

// Problem constants (from reference)
constexpr int NN   = 100000;   // nodes
constexpr int IND  = 256;      // input dim
constexpr int HIDD = 256;      // hidden dim
constexpr int EMBD = 64;       // embedding dim
constexpr int EE   = 3200000;  // edges
// CSR coarse partition: bucket = row >> CB (256 rows per bucket)
constexpr int CB    = 8;
constexpr int NB    = ((NN - 1) >> CB) + 1;   // 391
constexpr int NBP   = 512;                    // padded for LDS scan
constexpr int CHUNK = 4096;                   // edges per partA block
constexpr int EPT   = CHUNK / 256;            // 16 edges per thread
constexpr int NCHUNK = (EE + CHUNK - 1) / CHUNK;  // 782
// R14: direct-scatter CSR build regressed (8x write-allocate amplification);
// partA/partB LDS counting-sort is load-bearing.
// R15-R17: gemm2-into-spmm1 fusion tried 3 ways (567/521/534us) vs unfused
// 510us — epilogue/imbalance overhead always exceeds the ~17us traffic win.
// ABANDONED; this file is the R6 structure (best measured, 509.9us) plus:
// R18: spmm1 column-sliced for L2 residency. h0 is 25.6MB vs 4MB per-XCD L2
// (~57% hit, gather service capped ~3.5TB/s). 8 slices x 32 dims = 3.2MB
// EACH FITS L2. Slice-major grid -> concurrent blocks share one slice ->
// gathers become L2 hits. Cost: edges re-read 8x (streaming, L3-hot) and
// 8x per-row epilogue. 8 lanes/edge x 4B, 8 edges per gather instr.
constexpr int GMT    = 8;
constexpr int GROWS  = GMT * 16;                        // 128
constexpr int GGRID  = (NN + GROWS - 1) / GROWS;        // 782
constexpr int APITCH = 264;  // bf16 elems per row (256 + 8 pad = 528B, bank-balanced)
constexpr int NRB1   = NN / 4;                          // 25000 row-blocks (4 rows each)
#define EPS_BN 1e-3f

typedef short  short8  __attribute__((ext_vector_type(8)));
typedef float  floatx4 __attribute__((ext_vector_type(4)));
typedef float  floatx2 __attribute__((ext_vector_type(2)));

static __device__ __forceinline__ unsigned short f2bf(float f) {
  __hip_bfloat16 b = __float2bfloat16(f);
  union { __hip_bfloat16 b; unsigned short u; } cv;
  cv.b = b;
  return cv.u;
}
static __device__ __forceinline__ float bf2f(unsigned short u) {
  return __uint_as_float(((unsigned)u) << 16);
}
static __device__ __forceinline__ unsigned char f2fp8(float f) {
  // v_cvt_pk_fp8_f32: OCP e4m3fn on gfx950
  return (unsigned char)__builtin_amdgcn_cvt_pk_fp8_f32(f, f, 0, false);
}

// ---- swizzle weights into MFMA B-fragment layout -----------------------------
__global__ __launch_bounds__(256) void swz_w1_kernel(
    const float* __restrict__ w1, unsigned short* __restrict__ w1s) {
  const int t = blockIdx.x * blockDim.x + threadIdx.x;  // 8192 threads
  const int lane = t & 63;
  const int f = t >> 6;          // 0..127
  const int kt = f >> 4;         // 0..7
  const int nt = f & 15;         // 0..15
  const int n = nt * 16 + (lane & 15);
#pragma unroll
  for (int j = 0; j < 8; ++j) {
    const int k = kt * 32 + (lane >> 4) * 8 + j;
    w1s[(size_t)(f * 64 + lane) * 8 + j] = f2bf(w1[k * HIDD + n]);
  }
}

__global__ __launch_bounds__(256) void swz_w2_kernel(
    const float* __restrict__ w2, unsigned short* __restrict__ w2s) {
  const int t = blockIdx.x * blockDim.x + threadIdx.x;  // 2048 threads
  const int lane = t & 63;
  const int f = t >> 6;          // 0..31
  const int kt = f >> 2;         // 0..7
  const int nt = f & 3;          // 0..3
  const int n = nt * 16 + (lane & 15);
#pragma unroll
  for (int j = 0; j < 8; ++j) {
    const int k = kt * 32 + (lane >> 4) * 8 + j;
    w2s[(size_t)(f * 64 + lane) * 8 + j] = f2bf(w2[k * EMBD + n]);
  }
}

// ---------------- GEMM1 (MFMA): h0(fp8) = bf16(x) @ w1 -----------------------
// 782 blocks x 8 m-tiles. A tile (16x256 f32) reg-staged -> bf16 LDS (dbuf),
// one barrier per m-tile. Each x byte fetched exactly once per block.
__global__ __launch_bounds__(512) void gemm1_mfma(
    const float* __restrict__ x, const unsigned short* __restrict__ w1s,
    unsigned char* __restrict__ h0) {
  __shared__ unsigned short sa[2][16][APITCH];  // 16.9 KB
  const int tid  = threadIdx.x;
  const int lane = tid & 63;
  const int wave = tid >> 6;   // 0..7
  const int quad = lane >> 4;
  const int l15  = lane & 15;
  // B fragments: wave covers cols [wave*32, wave*32+32) as 2 n-tiles of 16
  const short8* w1v = (const short8*)w1s;
  short8 bf[2][8];
#pragma unroll
  for (int nt2 = 0; nt2 < 2; ++nt2)
#pragma unroll
    for (int kt = 0; kt < 8; ++kt)
      bf[nt2][kt] = w1v[(size_t)(kt * 16 + wave * 2 + nt2) * 64 + lane];

  const int mbase = blockIdx.x * GROWS;
  // staging: thread t covers floats [t*8, t*8+8) of the 16x256 tile
  const int srow = tid >> 5;          // 0..15
  const int scol = (tid & 31) * 8;    // float col, 32B per thread

  auto srcp = [&](int mt) -> const float* {
    int r = mbase + mt * 16 + srow;
    if (r >= NN) r = NN - 1;          // clamp (stores are guarded)
    return x + (size_t)r * IND + scol;
  };

  // prologue: stage tile 0 into buf 0
  {
    const float* p = srcp(0);
    float4 g0 = *(const float4*)(p);
    float4 g1 = *(const float4*)(p + 4);
    short8 s;
    s[0] = (short)f2bf(g0.x); s[1] = (short)f2bf(g0.y);
    s[2] = (short)f2bf(g0.z); s[3] = (short)f2bf(g0.w);
    s[4] = (short)f2bf(g1.x); s[5] = (short)f2bf(g1.y);
    s[6] = (short)f2bf(g1.z); s[7] = (short)f2bf(g1.w);
    *(short8*)&sa[0][srow][(tid & 31) * 8] = s;
  }

#pragma unroll
  for (int mt = 0; mt < GMT; ++mt) {
    const int cur = mt & 1;
    // issue next-tile global loads (in flight across the MFMA phase)
    float4 g0, g1;
    if (mt + 1 < GMT) {
      const float* p = srcp(mt + 1);
      g0 = *(const float4*)(p);
      g1 = *(const float4*)(p + 4);
    }
    __syncthreads();  // buf[cur] writes visible; prev reads of buf[cur^1] done
    // A-frags from LDS + MFMA
    floatx4 c0 = {0.f, 0.f, 0.f, 0.f};
    floatx4 c1 = {0.f, 0.f, 0.f, 0.f};
#pragma unroll
    for (int kt = 0; kt < 8; ++kt) {
      short8 a = *(const short8*)&sa[cur][l15][quad * 8 + kt * 32];
      c0 = __builtin_amdgcn_mfma_f32_16x16x32_bf16(a, bf[0][kt], c0, 0, 0, 0);
      c1 = __builtin_amdgcn_mfma_f32_16x16x32_bf16(a, bf[1][kt], c1, 0, 0, 0);
    }
    // C/D layout: col = lane&15, row = quad*4 + reg  [verified m89/m91]
    const int m0 = mbase + mt * 16;
    if (m0 < NN) {  // NN % 16 == 0 -> whole m-tile valid or none
      unsigned char* o = h0 + (size_t)(m0 + quad * 4) * HIDD + wave * 32 + l15;
#pragma unroll
      for (int r = 0; r < 4; ++r) {
        o[(size_t)r * HIDD]      = f2fp8(c0[r]);
        o[(size_t)r * HIDD + 16] = f2fp8(c1[r]);
      }
    }
    // convert staged regs -> write other buffer (read next iter after barrier)
    if (mt + 1 < GMT) {
      short8 s;
      s[0] = (short)f2bf(g0.x); s[1] = (short)f2bf(g0.y);
      s[2] = (short)f2bf(g0.z); s[3] = (short)f2bf(g0.w);
      s[4] = (short)f2bf(g1.x); s[5] = (short)f2bf(g1.y);
      s[6] = (short)f2bf(g1.z); s[7] = (short)f2bf(g1.w);
      *(short8*)&sa[cur ^ 1][srow][(tid & 31) * 8] = s;
    }
  }
}

// ---------------- GEMM2 (MFMA): z0(fp8) = h(bf16) @ w2 -----------------------
// Same LDS-dbuf template; h already bf16 so staging is a straight copy.
__global__ __launch_bounds__(256) void gemm2_mfma(
    const unsigned short* __restrict__ hb, const unsigned short* __restrict__ w2s,
    unsigned char* __restrict__ z0) {
  __shared__ unsigned short sa[2][16][APITCH];  // 16.9 KB
  const int tid  = threadIdx.x;
  const int lane = tid & 63;
  const int wave = tid >> 6;   // 0..3
  const int quad = lane >> 4;
  const int l15  = lane & 15;
  const short8* w2v = (const short8*)w2s;
  short8 bf[8];
#pragma unroll
  for (int kt = 0; kt < 8; ++kt)
    bf[kt] = w2v[(size_t)(kt * 4 + wave) * 64 + lane];

  const int mbase = blockIdx.x * GROWS;
  // staging: thread t covers shorts [t*16, t*16+16) of the 16x256 bf16 tile
  const int srow = tid >> 4;          // 0..15
  const int scol = (tid & 15) * 16;   // short col, 32B per thread

  auto srcp = [&](int mt) -> const unsigned short* {
    int r = mbase + mt * 16 + srow;
    if (r >= NN) r = NN - 1;
    return hb + (size_t)r * HIDD + scol;
  };

  {
    const unsigned short* p = srcp(0);
    short8 g0 = *(const short8*)(p);
    short8 g1 = *(const short8*)(p + 8);
    *(short8*)&sa[0][srow][scol]     = g0;
    *(short8*)&sa[0][srow][scol + 8] = g1;
  }

#pragma unroll
  for (int mt = 0; mt < GMT; ++mt) {
    const int cur = mt & 1;
    short8 g0, g1;
    if (mt + 1 < GMT) {
      const unsigned short* p = srcp(mt + 1);
      g0 = *(const short8*)(p);
      g1 = *(const short8*)(p + 8);
    }
    __syncthreads();
    floatx4 c = {0.f, 0.f, 0.f, 0.f};
#pragma unroll
    for (int kt = 0; kt < 8; ++kt) {
      short8 a = *(const short8*)&sa[cur][l15][quad * 8 + kt * 32];
      c = __builtin_amdgcn_mfma_f32_16x16x32_bf16(a, bf[kt], c, 0, 0, 0);
    }
    const int m0 = mbase + mt * 16;
    if (m0 < NN) {
      unsigned char* o = z0 + (size_t)(m0 + quad * 4) * EMBD + wave * 16 + l15;
#pragma unroll
      for (int r = 0; r < 4; ++r) o[(size_t)r * EMBD] = f2fp8(c[r]);
    }
    if (mt + 1 < GMT) {
      *(short8*)&sa[cur ^ 1][srow][scol]     = g0;
      *(short8*)&sa[cur ^ 1][srow][scol + 8] = g1;
    }
  }
}

// ---------------- CSR build --------------------------------------------------
// Bucket-level histogram: LDS counters per chunk, <=NB global atomics/chunk.
__global__ __launch_bounds__(256) void histb_kernel(
    const int* __restrict__ row, int* __restrict__ bcnt) {
  __shared__ int lcnt[NB];
  for (int i = threadIdx.x; i < NB; i += 256) lcnt[i] = 0;
  __syncthreads();
  const int base = blockIdx.x * CHUNK;
  const int lim  = min(EE - base, CHUNK);
  for (int i = threadIdx.x; i < lim; i += 256)
    atomicAdd(&lcnt[row[base + i] >> CB], 1);
  __syncthreads();
  for (int i = threadIdx.x; i < NB; i += 256) {
    const int c = lcnt[i];
    if (c) atomicAdd(&bcnt[i * 16], c);
  }
}

// Scan 391 bucket counts -> bucket_start (compact) + bcur (padded cursors)
__global__ __launch_bounds__(512) void bscan_kernel(
    const int* __restrict__ bcnt, int* __restrict__ bucket_start,
    int* __restrict__ bcur) {
  __shared__ int lds[512];
  int v = (threadIdx.x < NB) ? bcnt[threadIdx.x * 16] : 0;
  lds[threadIdx.x] = v;
  for (int off = 1; off < 512; off <<= 1) {
    __syncthreads();
    int t = (threadIdx.x >= off) ? lds[threadIdx.x - off] : 0;
    __syncthreads();
    lds[threadIdx.x] += t;
  }
  __syncthreads();
  if (threadIdx.x < NB) {
    const int excl = lds[threadIdx.x] - v;
    bucket_start[threadIdx.x] = excl;
    bcur[threadIdx.x * 16] = excl;
  }
  if (threadIdx.x == 0) bucket_start[NB] = EE;
}

// Pass A: LDS counting-sort each 4096-edge chunk by coarse bucket, then flush
// piecewise-contiguous runs with ONE global atomic per (block,bucket).
// Record packs (row:17 | col:17 | val_bf16:16) into 8B.
__global__ __launch_bounds__(256) void partA_kernel(
    const int* __restrict__ row, const int* __restrict__ col,
    const float* __restrict__ val, int* __restrict__ bcur,
    unsigned long long* __restrict__ staged) {
  __shared__ unsigned long long sbuf[CHUNK];  // 32 KB
  __shared__ int cnt[NBP];
  __shared__ int scn[NBP];
  __shared__ int cur[NB];
  __shared__ int gofs[NB];
  const int base = blockIdx.x * CHUNK;
  const int lim  = min(EE - base, CHUNK);
  for (int i = threadIdx.x; i < NBP; i += 256) cnt[i] = 0;
  __syncthreads();
  // load + histogram (records kept in registers)
  unsigned long long rec[EPT];
  int bkt[EPT];
#pragma unroll
  for (int j = 0; j < EPT; ++j) {
    const int idx = threadIdx.x + j * 256;
    bkt[j] = -1;
    if (idx < lim) {
      const int e = base + idx;
      const int r = row[e];
      const int c = col[e];
      const unsigned short v = f2bf(val[e]);
      rec[j] = ((unsigned long long)r << 33) | ((unsigned long long)c << 16) | v;
      bkt[j] = r >> CB;
      atomicAdd(&cnt[bkt[j]], 1);
    }
  }
  __syncthreads();
  // inclusive scan of cnt -> scn (512 entries, 2 per thread)
  for (int i = threadIdx.x; i < NBP; i += 256) scn[i] = cnt[i];
  __syncthreads();
  for (int off = 1; off < NBP; off <<= 1) {
    const int i0 = threadIdx.x, i1 = threadIdx.x + 256;
    const int t0 = (i0 >= off) ? scn[i0 - off] : 0;
    const int t1 = (i1 >= off) ? scn[i1 - off] : 0;
    __syncthreads();
    scn[i0] += t0;
    scn[i1] += t1;
    __syncthreads();
  }
  // placement cursors = exclusive start
  for (int b = threadIdx.x; b < NB; b += 256) cur[b] = scn[b] - cnt[b];
  __syncthreads();
  // reorder into LDS (no line granularity in LDS -> scatter is fine)
#pragma unroll
  for (int j = 0; j < EPT; ++j)
    if (bkt[j] >= 0) {
      const int p = atomicAdd(&cur[bkt[j]], 1);
      sbuf[p] = rec[j];
    }
  __syncthreads();
  // reserve global ranges: one atomic per non-empty bucket
  for (int b = threadIdx.x; b < NB; b += 256) {
    const int c = cnt[b];
    const int g = (c > 0) ? atomicAdd(&bcur[b * 16], c) : 0;
    gofs[b] = g - (scn[b] - c);  // out = gofs[b] + local_slot
  }
  __syncthreads();
  // flush: consecutive slots of a bucket -> consecutive global addresses
  for (int s = threadIdx.x; s < lim; s += 256) {
    const unsigned long long rc = sbuf[s];
    const int b = (int)(rc >> (33 + CB));
    staged[(size_t)(gofs[b] + s)] = rc;
  }
}

// Pass B: one block per coarse bucket (256 rows). Pass 1 histograms rows
// (high-dword reads) -> LDS scan -> writes row_start + cursors. Pass 2
// scatters records into the block-local ~65KB window (L2-hot on re-read).
__global__ __launch_bounds__(256) void partB_kernel(
    const int* __restrict__ bucket_start,
    const unsigned long long* __restrict__ staged,
    int2* __restrict__ edges, int* __restrict__ row_start) {
  __shared__ int cnt[1 << CB];
  __shared__ int ofs[1 << CB];
  const int b  = blockIdx.x;
  const int r0 = b << CB;
  const int rn = min(NN - r0, 1 << CB);
  const int s  = bucket_start[b];
  const int e  = bucket_start[b + 1];
  cnt[threadIdx.x] = 0;
  __syncthreads();
  // pass 1: row histogram (read only the high dword of each record)
  const unsigned* hi = (const unsigned*)staged;
  for (int p = s + threadIdx.x; p < e; p += 256) {
    const unsigned hw = hi[2 * p + 1];
    const int r = (int)((hw >> 1) & 0x1FFFF);
    atomicAdd(&cnt[r - r0], 1);
  }
  __syncthreads();
  // exclusive scan of 256 bins
  const int v = cnt[threadIdx.x];
  ofs[threadIdx.x] = v;
  for (int off = 1; off < 256; off <<= 1) {
    __syncthreads();
    const int t = (threadIdx.x >= off) ? ofs[threadIdx.x - off] : 0;
    __syncthreads();
    ofs[threadIdx.x] += t;
  }
  __syncthreads();
  const int excl = ofs[threadIdx.x] - v;
  if ((int)threadIdx.x < rn) row_start[r0 + threadIdx.x] = s + excl;
  if (b == NB - 1 && threadIdx.x == 0) row_start[NN] = e;
  __syncthreads();
  cnt[threadIdx.x] = s + excl;  // reuse as cursors
  __syncthreads();
  // pass 2: scatter into final CSR order
  for (int p = s + threadIdx.x; p < e; p += 256) {
    const unsigned long long rc = staged[p];
    const int r = (int)(rc >> 33);
    const int c = (int)((rc >> 16) & 0x1FFFF);
    const float vv = bf2f((unsigned short)(rc & 0xFFFF));
    const int q = atomicAdd(&cnt[r - r0], 1);
    int2 pk; pk.x = c << 6; pk.y = __float_as_int(vv);  // col*64 pre-scaled
    edges[q] = pk;
  }
}

// ------- SpMM1 + BN1 + ReLU (R18: column-sliced): h = relu(bn1(A @ h0)) ------
// Grid = 8 slices x 25000 row-blocks, SLICE-MAJOR: concurrent blocks share
// one 3.2MB h0 column-slice -> slice resident in every XCD's 4MB L2 ->
// gathers are L2 hits instead of ~3.5TB/s fabric misses. 8 lanes/edge x 4B,
// 8 edges per gather instruction; reduce over the 8 edge-slots via shfl_xor
// (8,16,32); BN for this slice's 4 dims; 8B store (8 lanes x 8B = 64B/row).
__global__ __launch_bounds__(256, 8) void spmm1_kernel(
    const unsigned char* __restrict__ h0, const int* __restrict__ row_start,
    const int2* __restrict__ edges,
    const float* __restrict__ gamma, const float* __restrict__ beta,
    const float* __restrict__ mean, const float* __restrict__ var,
    unsigned short* __restrict__ h) {
  const int sb   = blockIdx.x / NRB1;   // slice 0..7 (slice-major dispatch)
  const int rb   = blockIdx.x % NRB1;
  const int lane = threadIdx.x & 63;
  const int wave = threadIdx.x >> 6;    // 0..3: row within the row-block
  const int grp8 = lane >> 3;           // 0..7: edge slot
  const int t8   = lane & 7;            // 0..7: dim-quad within slice
  const int doff = sb * 32 + t8 * 4;    // dim (== byte, fp8) offset in h0 row

  const int row = rb * 4 + wave;
  const int s = row_start[row];
  const int e = row_start[row + 1];
  const unsigned long long* e64 = (const unsigned long long*)edges;

  floatx2 a01 = {0.f, 0.f};
  floatx2 a23 = {0.f, 0.f};
  for (int p = s; p < e; p += 8) {
    const int idx = p + grp8;
    const bool valid = idx < e;
    const unsigned long long rec = e64[valid ? idx : s];  // s valid: loop entered
    const unsigned coff = (unsigned)(rec & 0xFFFFFFFFu);  // col*64 (pre-scaled)
    const float v = valid ? __uint_as_float((unsigned)(rec >> 32)) : 0.f;
    const unsigned g = *(const unsigned*)(h0 + (size_t)coff * 4 + doff);
    const floatx2 v2 = {v, v};
    a01 += __builtin_amdgcn_cvt_pk_f32_fp8(g, false) * v2;
    a23 += __builtin_amdgcn_cvt_pk_f32_fp8(g, true)  * v2;
  }
  // reduce across the 8 edge slots (lanes l, l^8, l^16, l^32 share dims)
  a01[0] += __shfl_xor(a01[0], 8);  a01[1] += __shfl_xor(a01[1], 8);
  a23[0] += __shfl_xor(a23[0], 8);  a23[1] += __shfl_xor(a23[1], 8);
  a01[0] += __shfl_xor(a01[0], 16); a01[1] += __shfl_xor(a01[1], 16);
  a23[0] += __shfl_xor(a23[0], 16); a23[1] += __shfl_xor(a23[1], 16);
  a01[0] += __shfl_xor(a01[0], 32); a01[1] += __shfl_xor(a01[1], 32);
  a23[0] += __shfl_xor(a23[0], 32); a23[1] += __shfl_xor(a23[1], 32);
  // BN + ReLU + bf16 pack + store: one edge-slot group writes (8 lanes x 8B)
  if (grp8 == 0) {
    const int d = doff;
    float4 g4 = *(const float4*)(gamma + d);
    float4 b4 = *(const float4*)(beta + d);
    float4 m4 = *(const float4*)(mean + d);
    float4 v4 = *(const float4*)(var + d);
    const unsigned short o0 =
        f2bf(fmaxf(fmaf((a01[0] - m4.x) * rsqrtf(v4.x + EPS_BN), g4.x, b4.x), 0.f));
    const unsigned short o1 =
        f2bf(fmaxf(fmaf((a01[1] - m4.y) * rsqrtf(v4.y + EPS_BN), g4.y, b4.y), 0.f));
    const unsigned short o2 =
        f2bf(fmaxf(fmaf((a23[0] - m4.z) * rsqrtf(v4.z + EPS_BN), g4.z, b4.z), 0.f));
    const unsigned short o3 =
        f2bf(fmaxf(fmaf((a23[1] - m4.w) * rsqrtf(v4.w + EPS_BN), g4.w, b4.w), 0.f));
    const unsigned long long ow =
        (unsigned long long)o0 | ((unsigned long long)o1 << 16) |
        ((unsigned long long)o2 << 32) | ((unsigned long long)o3 << 48);
    *(unsigned long long*)(h + (size_t)row * HIDD + d) = ow;
  }
}

// ---------------- SpMM2 + BN2: out = bn2(A @ z0(fp8)) ------------------------
// R6's proven exact-trip-count structure (bulk full-16s, 4-wise tail).
__global__ __launch_bounds__(256, 8) void spmm2_kernel(
    const unsigned char* __restrict__ z0, const int* __restrict__ row_start,
    const int2* __restrict__ edges,
    const float* __restrict__ gamma, const float* __restrict__ beta,
    const float* __restrict__ mean, const float* __restrict__ var,
    float* __restrict__ out) {
  const int row  = (blockIdx.x * blockDim.x + threadIdx.x) >> 6;
  const int lane = threadIdx.x & 63;
  const int grp  = lane >> 4;      // 0..3
  const int t    = lane & 15;      // dims [t*4, t*4+4)
  const int t4   = t * 4;
  const int s = row_start[row];
  const int e = row_start[row + 1];
  floatx2 a01 = {0.f, 0.f};
  floatx2 a23 = {0.f, 0.f};
  const int ebulk = s + ((e - s) & ~15);
  int p = s;
  for (; p < ebulk; p += 16) {
    unsigned coff[4];
    float    vv4[4];
#pragma unroll
    for (int k = 0; k < 4; ++k) {
      const int2 er = edges[p + k * 4 + grp];
      coff[k] = (unsigned)er.x;                    // col*64
      vv4[k]  = __int_as_float(er.y);
    }
    unsigned gg[4];
#pragma unroll
    for (int k = 0; k < 4; ++k)
      gg[k] = *(const unsigned*)(z0 + (size_t)coff[k] + t4);
#pragma unroll
    for (int k = 0; k < 4; ++k) {
      const floatx2 v2 = {vv4[k], vv4[k]};
      a01 += __builtin_amdgcn_cvt_pk_f32_fp8(gg[k], false) * v2;
      a23 += __builtin_amdgcn_cvt_pk_f32_fp8(gg[k], true)  * v2;
    }
  }
  for (; p < e; p += 4) {
    const int idx = p + grp;
    const bool valid = idx < e;
    const int2 er = edges[valid ? idx : e - 1];
    const unsigned coff = (unsigned)er.x;
    const float vvs = valid ? __int_as_float(er.y) : 0.f;
    const unsigned gg = *(const unsigned*)(z0 + (size_t)coff + t4);
    const floatx2 v2 = {vvs, vvs};
    a01 += __builtin_amdgcn_cvt_pk_f32_fp8(gg, false) * v2;
    a23 += __builtin_amdgcn_cvt_pk_f32_fp8(gg, true)  * v2;
  }
  a01[0] += __shfl_xor(a01[0], 16); a01[1] += __shfl_xor(a01[1], 16);
  a23[0] += __shfl_xor(a23[0], 16); a23[1] += __shfl_xor(a23[1], 16);
  a01[0] += __shfl_xor(a01[0], 32); a01[1] += __shfl_xor(a01[1], 32);
  a23[0] += __shfl_xor(a23[0], 32); a23[1] += __shfl_xor(a23[1], 32);
  // lane (grp,t) writes dim t*4 + grp
  float av;
  if (grp == 0)      av = a01[0];
  else if (grp == 1) av = a01[1];
  else if (grp == 2) av = a23[0];
  else               av = a23[1];
  const int d = t4 + grp;
  const float r = fmaf((av - mean[d]) * rsqrtf(var[d] + EPS_BN), gamma[d],
                       beta[d]);
  out[(size_t)row * EMBD + d] = r;
}

extern "C" void kernel_launch(void* const* d_in, const int* in_sizes, int n_in,
                              void* d_out, int out_size, void* d_ws, size_t ws_size,
                              hipStream_t stream) {
  const float* x        = (const float*)d_in[0];
  const int*   edge_row = (const int*)d_in[1];
  const int*   edge_col = (const int*)d_in[2];
  const float* edge_val = (const float*)d_in[3];
  const float* w1       = (const float*)d_in[4];
  const float* w2       = (const float*)d_in[5];
  const float* gamma1   = (const float*)d_in[6];
  const float* beta1    = (const float*)d_in[7];
  const float* mean1    = (const float*)d_in[8];
  const float* var1     = (const float*)d_in[9];
  const float* gamma2   = (const float*)d_in[10];
  const float* beta2    = (const float*)d_in[11];
  const float* mean2    = (const float*)d_in[12];
  const float* var2     = (const float*)d_in[13];
  float* out = (float*)d_out;

  // Workspace layout (256B aligned). Total ~110 MB.
  char* ws = (char*)d_ws;
  size_t off = 0;
  auto alloc = [&](size_t bytes) -> void* {
    void* p = ws + off;
    off = (off + bytes + 255) & ~(size_t)255;
    return p;
  };
  unsigned char*  h0  = (unsigned char*)alloc((size_t)NN * HIDD);       // 25.6MB fp8
  unsigned short* h   = (unsigned short*)alloc((size_t)NN * HIDD * 2);  // 51.2MB bf16
  // staged records alias h: 25.6MB, dead before spmm1 writes h
  unsigned long long* staged = (unsigned long long*)h;
  unsigned char*  z0  = (unsigned char*)alloc((size_t)NN * EMBD);       // 6.4MB fp8
  unsigned short* w1s = (unsigned short*)alloc((size_t)IND * HIDD * 2);
  unsigned short* w2s = (unsigned short*)alloc((size_t)HIDD * EMBD * 2);
  int*   row_start    = (int*)alloc((size_t)(NN + 1) * 4);
  int*   bcnt         = (int*)alloc((size_t)NB * 16 * 4);               // 25KB padded
  int*   bcur         = (int*)alloc((size_t)NB * 16 * 4);               // 25KB padded
  int*   bucket_start = (int*)alloc((size_t)(NB + 1) * 4);
  int2*  edges        = (int2*)alloc((size_t)EE * 8);                   // 25.6MB

  // weight swizzles (independent of CSR build)
  swz_w1_kernel<<<8192 / 256, 256, 0, stream>>>(w1, w1s);
  swz_w2_kernel<<<2048 / 256, 256, 0, stream>>>(w2, w2s);

  // CSR build: bucket hist -> bucket scan -> LDS counting-sort partition (A)
  //            -> per-bucket row_start + sort (B)
  hipMemsetAsync(bcnt, 0, (size_t)NB * 16 * 4, stream);
  histb_kernel<<<NCHUNK, 256, 0, stream>>>(edge_row, bcnt);
  bscan_kernel<<<1, 512, 0, stream>>>(bcnt, bucket_start, bcur);
  partA_kernel<<<NCHUNK, 256, 0, stream>>>(
      edge_row, edge_col, edge_val, bcur, staged);
  partB_kernel<<<NB, 256, 0, stream>>>(bucket_start, staged, edges, row_start);

  // Layer 1: h0 = fp8(bf16(x) @ w1) ; h = bf16(relu(bn1(A @ h0)))
  gemm1_mfma<<<GGRID, 512, 0, stream>>>(x, w1s, h0);
  spmm1_kernel<<<8 * NRB1, 256, 0, stream>>>(h0, row_start, edges,
                                             gamma1, beta1, mean1, var1, h);
  // Layer 2: z0 = fp8(h @ w2) ; out = bn2(A @ z0)
  gemm2_mfma<<<GGRID, 256, 0, stream>>>(h, w2s, z0);
  spmm2_kernel<<<NN / 4, 256, 0, stream>>>(z0, row_start, edges,
                                           gamma2, beta2, mean2, var2, out);
}

// Round 14
// 610.248 us; speedup vs baseline: 1.4485x; 1.4485x over previous
//
#include <hip/hip_runtime.h>
#include <hip/hip_bf16.h>

// Problem constants (from reference)
constexpr int NN   = 100000;   // nodes
constexpr int IND  = 256;      // input dim
constexpr int HIDD = 256;      // hidden dim
constexpr int EMBD = 64;       // embedding dim
constexpr int EE   = 3200000;  // edges
// CSR coarse partition: bucket = row >> CB (256 rows per bucket)
constexpr int CB    = 8;
constexpr int NB    = ((NN - 1) >> CB) + 1;   // 391
constexpr int NBP   = 512;                    // padded for LDS scan
constexpr int CHUNK = 4096;                   // edges per partA block
constexpr int EPT   = CHUNK / 256;            // 16 edges per thread
constexpr int NCHUNK = (EE + CHUNK - 1) / CHUNK;  // 782
// LEDGER of refuted directions (do not retry):
//  R13 direct-scatter CSR: 8B random stores -> 8x write-allocate (790us).
//  R15-R17 gemm2-into-spmm1 fusion: 567/521/534 vs 510 unfused.
//  R18 column-sliced spmm1: line granularity + 8x XCD fill replication +
//   8x edge re-read -> 884us. spmm1 is fabric-service bound (~410MB @
//   ~3.8TB/s); 4 gather formulations within 8% -> STRUCTURAL CEILING.
// R19 (this file): R6/R8 proven kernels + CSR-build trim: histb+bscan
// replaced by histr+scanA+scanB (row hist gives bucket totals free);
// partB loses its hist pass (cursors precomputed into row_start by fin).
// R20: resubmission of R19 — container infra failure, kernel never ran.
constexpr int GMT    = 8;
constexpr int GROWS  = GMT * 16;                        // 128
constexpr int GGRID  = (NN + GROWS - 1) / GROWS;        // 782
constexpr int APITCH = 264;  // bf16 elems per row (256 + 8 pad = 528B, bank-balanced)
#define EPS_BN 1e-3f

typedef short  short8  __attribute__((ext_vector_type(8)));
typedef float  floatx4 __attribute__((ext_vector_type(4)));
typedef float  floatx2 __attribute__((ext_vector_type(2)));

static __device__ __forceinline__ unsigned short f2bf(float f) {
  __hip_bfloat16 b = __float2bfloat16(f);
  union { __hip_bfloat16 b; unsigned short u; } cv;
  cv.b = b;
  return cv.u;
}
static __device__ __forceinline__ float bf2f(unsigned short u) {
  return __uint_as_float(((unsigned)u) << 16);
}
static __device__ __forceinline__ unsigned char f2fp8(float f) {
  // v_cvt_pk_fp8_f32: OCP e4m3fn on gfx950
  return (unsigned char)__builtin_amdgcn_cvt_pk_fp8_f32(f, f, 0, false);
}

// ---- swizzle weights into MFMA B-fragment layout -----------------------------
__global__ __launch_bounds__(256) void swz_w1_kernel(
    const float* __restrict__ w1, unsigned short* __restrict__ w1s) {
  const int t = blockIdx.x * blockDim.x + threadIdx.x;  // 8192 threads
  const int lane = t & 63;
  const int f = t >> 6;          // 0..127
  const int kt = f >> 4;         // 0..7
  const int nt = f & 15;         // 0..15
  const int n = nt * 16 + (lane & 15);
#pragma unroll
  for (int j = 0; j < 8; ++j) {
    const int k = kt * 32 + (lane >> 4) * 8 + j;
    w1s[(size_t)(f * 64 + lane) * 8 + j] = f2bf(w1[k * HIDD + n]);
  }
}

__global__ __launch_bounds__(256) void swz_w2_kernel(
    const float* __restrict__ w2, unsigned short* __restrict__ w2s) {
  const int t = blockIdx.x * blockDim.x + threadIdx.x;  // 2048 threads
  const int lane = t & 63;
  const int f = t >> 6;          // 0..31
  const int kt = f >> 2;         // 0..7
  const int nt = f & 3;          // 0..3
  const int n = nt * 16 + (lane & 15);
#pragma unroll
  for (int j = 0; j < 8; ++j) {
    const int k = kt * 32 + (lane >> 4) * 8 + j;
    w2s[(size_t)(f * 64 + lane) * 8 + j] = f2bf(w2[k * EMBD + n]);
  }
}

// ---------------- GEMM1 (MFMA): h0(fp8) = bf16(x) @ w1 -----------------------
// 782 blocks x 8 m-tiles. A tile (16x256 f32) reg-staged -> bf16 LDS (dbuf),
// one barrier per m-tile. Each x byte fetched exactly once per block.
__global__ __launch_bounds__(512) void gemm1_mfma(
    const float* __restrict__ x, const unsigned short* __restrict__ w1s,
    unsigned char* __restrict__ h0) {
  __shared__ unsigned short sa[2][16][APITCH];  // 16.9 KB
  const int tid  = threadIdx.x;
  const int lane = tid & 63;
  const int wave = tid >> 6;   // 0..7
  const int quad = lane >> 4;
  const int l15  = lane & 15;
  // B fragments: wave covers cols [wave*32, wave*32+32) as 2 n-tiles of 16
  const short8* w1v = (const short8*)w1s;
  short8 bf[2][8];
#pragma unroll
  for (int nt2 = 0; nt2 < 2; ++nt2)
#pragma unroll
    for (int kt = 0; kt < 8; ++kt)
      bf[nt2][kt] = w1v[(size_t)(kt * 16 + wave * 2 + nt2) * 64 + lane];

  const int mbase = blockIdx.x * GROWS;
  // staging: thread t covers floats [t*8, t*8+8) of the 16x256 tile
  const int srow = tid >> 5;          // 0..15
  const int scol = (tid & 31) * 8;    // float col, 32B per thread

  auto srcp = [&](int mt) -> const float* {
    int r = mbase + mt * 16 + srow;
    if (r >= NN) r = NN - 1;          // clamp (stores are guarded)
    return x + (size_t)r * IND + scol;
  };

  // prologue: stage tile 0 into buf 0
  {
    const float* p = srcp(0);
    float4 g0 = *(const float4*)(p);
    float4 g1 = *(const float4*)(p + 4);
    short8 s;
    s[0] = (short)f2bf(g0.x); s[1] = (short)f2bf(g0.y);
    s[2] = (short)f2bf(g0.z); s[3] = (short)f2bf(g0.w);
    s[4] = (short)f2bf(g1.x); s[5] = (short)f2bf(g1.y);
    s[6] = (short)f2bf(g1.z); s[7] = (short)f2bf(g1.w);
    *(short8*)&sa[0][srow][(tid & 31) * 8] = s;
  }

#pragma unroll
  for (int mt = 0; mt < GMT; ++mt) {
    const int cur = mt & 1;
    // issue next-tile global loads (in flight across the MFMA phase)
    float4 g0, g1;
    if (mt + 1 < GMT) {
      const float* p = srcp(mt + 1);
      g0 = *(const float4*)(p);
      g1 = *(const float4*)(p + 4);
    }
    __syncthreads();  // buf[cur] writes visible; prev reads of buf[cur^1] done
    // A-frags from LDS + MFMA
    floatx4 c0 = {0.f, 0.f, 0.f, 0.f};
    floatx4 c1 = {0.f, 0.f, 0.f, 0.f};
#pragma unroll
    for (int kt = 0; kt < 8; ++kt) {
      short8 a = *(const short8*)&sa[cur][l15][quad * 8 + kt * 32];
      c0 = __builtin_amdgcn_mfma_f32_16x16x32_bf16(a, bf[0][kt], c0, 0, 0, 0);
      c1 = __builtin_amdgcn_mfma_f32_16x16x32_bf16(a, bf[1][kt], c1, 0, 0, 0);
    }
    // C/D layout: col = lane&15, row = quad*4 + reg  [verified m89/m91]
    const int m0 = mbase + mt * 16;
    if (m0 < NN) {  // NN % 16 == 0 -> whole m-tile valid or none
      unsigned char* o = h0 + (size_t)(m0 + quad * 4) * HIDD + wave * 32 + l15;
#pragma unroll
      for (int r = 0; r < 4; ++r) {
        o[(size_t)r * HIDD]      = f2fp8(c0[r]);
        o[(size_t)r * HIDD + 16] = f2fp8(c1[r]);
      }
    }
    // convert staged regs -> write other buffer (read next iter after barrier)
    if (mt + 1 < GMT) {
      short8 s;
      s[0] = (short)f2bf(g0.x); s[1] = (short)f2bf(g0.y);
      s[2] = (short)f2bf(g0.z); s[3] = (short)f2bf(g0.w);
      s[4] = (short)f2bf(g1.x); s[5] = (short)f2bf(g1.y);
      s[6] = (short)f2bf(g1.z); s[7] = (short)f2bf(g1.w);
      *(short8*)&sa[cur ^ 1][srow][(tid & 31) * 8] = s;
    }
  }
}

// ---------------- GEMM2 (MFMA): z0(fp8) = h(bf16) @ w2 -----------------------
// Same LDS-dbuf template; h already bf16 so staging is a straight copy.
__global__ __launch_bounds__(256) void gemm2_mfma(
    const unsigned short* __restrict__ hb, const unsigned short* __restrict__ w2s,
    unsigned char* __restrict__ z0) {
  __shared__ unsigned short sa[2][16][APITCH];  // 16.9 KB
  const int tid  = threadIdx.x;
  const int lane = tid & 63;
  const int wave = tid >> 6;   // 0..3
  const int quad = lane >> 4;
  const int l15  = lane & 15;
  const short8* w2v = (const short8*)w2s;
  short8 bf[8];
#pragma unroll
  for (int kt = 0; kt < 8; ++kt)
    bf[kt] = w2v[(size_t)(kt * 4 + wave) * 64 + lane];

  const int mbase = blockIdx.x * GROWS;
  // staging: thread t covers shorts [t*16, t*16+16) of the 16x256 bf16 tile
  const int srow = tid >> 4;          // 0..15
  const int scol = (tid & 15) * 16;   // short col, 32B per thread

  auto srcp = [&](int mt) -> const unsigned short* {
    int r = mbase + mt * 16 + srow;
    if (r >= NN) r = NN - 1;
    return hb + (size_t)r * HIDD + scol;
  };

  {
    const unsigned short* p = srcp(0);
    short8 g0 = *(const short8*)(p);
    short8 g1 = *(const short8*)(p + 8);
    *(short8*)&sa[0][srow][scol]     = g0;
    *(short8*)&sa[0][srow][scol + 8] = g1;
  }

#pragma unroll
  for (int mt = 0; mt < GMT; ++mt) {
    const int cur = mt & 1;
    short8 g0, g1;
    if (mt + 1 < GMT) {
      const unsigned short* p = srcp(mt + 1);
      g0 = *(const short8*)(p);
      g1 = *(const short8*)(p + 8);
    }
    __syncthreads();
    floatx4 c = {0.f, 0.f, 0.f, 0.f};
#pragma unroll
    for (int kt = 0; kt < 8; ++kt) {
      short8 a = *(const short8*)&sa[cur][l15][quad * 8 + kt * 32];
      c = __builtin_amdgcn_mfma_f32_16x16x32_bf16(a, bf[kt], c, 0, 0, 0);
    }
    const int m0 = mbase + mt * 16;
    if (m0 < NN) {
      unsigned char* o = z0 + (size_t)(m0 + quad * 4) * EMBD + wave * 16 + l15;
#pragma unroll
      for (int r = 0; r < 4; ++r) o[(size_t)r * EMBD] = f2fp8(c[r]);
    }
    if (mt + 1 < GMT) {
      *(short8*)&sa[cur ^ 1][srow][scol]     = g0;
      *(short8*)&sa[cur ^ 1][srow][scol + 8] = g1;
    }
  }
}

// ---------------- CSR build (R19) --------------------------------------------
// Row-level histogram (proven cheap in R13 — only the direct scatter was bad).
__global__ __launch_bounds__(256) void histr_kernel(
    const int* __restrict__ row, int* __restrict__ cnt) {
  const int i = blockIdx.x * 256 + threadIdx.x;
  if (i < EE) atomicAdd(&cnt[row[i]], 1);
}

// per-bucket (256 rows) exclusive scan of row counts; writes bucket totals
__global__ __launch_bounds__(256) void scanA_kernel(
    const int* __restrict__ cnt, int* __restrict__ excl,
    int* __restrict__ btot) {
  __shared__ int lds[256];
  const int r = blockIdx.x * 256 + threadIdx.x;
  const int v = (r < NN) ? cnt[r] : 0;
  lds[threadIdx.x] = v;
  for (int off = 1; off < 256; off <<= 1) {
    __syncthreads();
    const int t = (threadIdx.x >= off) ? lds[threadIdx.x - off] : 0;
    __syncthreads();
    lds[threadIdx.x] += t;
  }
  __syncthreads();
  if (r < NN) excl[r] = lds[threadIdx.x] - v;
  if (threadIdx.x == 255) btot[blockIdx.x] = lds[255];
}

// scan 391 bucket totals -> bucket_start (compact) + bcur (padded cursors)
__global__ __launch_bounds__(512) void scanB_kernel(
    const int* __restrict__ btot, int* __restrict__ bucket_start,
    int* __restrict__ bcur) {
  __shared__ int lds[512];
  const int v = (threadIdx.x < NB) ? btot[threadIdx.x] : 0;
  lds[threadIdx.x] = v;
  for (int off = 1; off < 512; off <<= 1) {
    __syncthreads();
    const int t = (threadIdx.x >= off) ? lds[threadIdx.x - off] : 0;
    __syncthreads();
    lds[threadIdx.x] += t;
  }
  __syncthreads();
  if (threadIdx.x < NB) {
    const int excl = lds[threadIdx.x] - v;
    bucket_start[threadIdx.x] = excl;
    bcur[threadIdx.x * 16] = excl;
  }
  if (threadIdx.x == 0) bucket_start[NB] = EE;
}

// row_start[r] = bucket_start[r>>8] + excl[r]
__global__ __launch_bounds__(256) void fin_kernel(
    const int* __restrict__ bucket_start, const int* __restrict__ excl,
    int* __restrict__ row_start) {
  const int r = blockIdx.x * 256 + threadIdx.x;
  if (r < NN) row_start[r] = bucket_start[r >> CB] + excl[r];
  if (r == 0) row_start[NN] = EE;
}

// Pass A: LDS counting-sort each 4096-edge chunk by coarse bucket, then flush
// piecewise-contiguous runs with ONE global atomic per (block,bucket).
// Record packs (row:17 | col:17 | val_bf16:16) into 8B. (R6-proven.)
__global__ __launch_bounds__(256) void partA_kernel(
    const int* __restrict__ row, const int* __restrict__ col,
    const float* __restrict__ val, int* __restrict__ bcur,
    unsigned long long* __restrict__ staged) {
  __shared__ unsigned long long sbuf[CHUNK];  // 32 KB
  __shared__ int cnt[NBP];
  __shared__ int scn[NBP];
  __shared__ int cur[NB];
  __shared__ int gofs[NB];
  const int base = blockIdx.x * CHUNK;
  const int lim  = min(EE - base, CHUNK);
  for (int i = threadIdx.x; i < NBP; i += 256) cnt[i] = 0;
  __syncthreads();
  // load + histogram (records kept in registers)
  unsigned long long rec[EPT];
  int bkt[EPT];
#pragma unroll
  for (int j = 0; j < EPT; ++j) {
    const int idx = threadIdx.x + j * 256;
    bkt[j] = -1;
    if (idx < lim) {
      const int e = base + idx;
      const int r = row[e];
      const int c = col[e];
      const unsigned short v = f2bf(val[e]);
      rec[j] = ((unsigned long long)r << 33) | ((unsigned long long)c << 16) | v;
      bkt[j] = r >> CB;
      atomicAdd(&cnt[bkt[j]], 1);
    }
  }
  __syncthreads();
  // inclusive scan of cnt -> scn (512 entries, 2 per thread)
  for (int i = threadIdx.x; i < NBP; i += 256) scn[i] = cnt[i];
  __syncthreads();
  for (int off = 1; off < NBP; off <<= 1) {
    const int i0 = threadIdx.x, i1 = threadIdx.x + 256;
    const int t0 = (i0 >= off) ? scn[i0 - off] : 0;
    const int t1 = (i1 >= off) ? scn[i1 - off] : 0;
    __syncthreads();
    scn[i0] += t0;
    scn[i1] += t1;
    __syncthreads();
  }
  // placement cursors = exclusive start
  for (int b = threadIdx.x; b < NB; b += 256) cur[b] = scn[b] - cnt[b];
  __syncthreads();
  // reorder into LDS (no line granularity in LDS -> scatter is fine)
#pragma unroll
  for (int j = 0; j < EPT; ++j)
    if (bkt[j] >= 0) {
      const int p = atomicAdd(&cur[bkt[j]], 1);
      sbuf[p] = rec[j];
    }
  __syncthreads();
  // reserve global ranges: one atomic per non-empty bucket
  for (int b = threadIdx.x; b < NB; b += 256) {
    const int c = cnt[b];
    const int g = (c > 0) ? atomicAdd(&bcur[b * 16], c) : 0;
    gofs[b] = g - (scn[b] - c);  // out = gofs[b] + local_slot
  }
  __syncthreads();
  // flush: consecutive slots of a bucket -> consecutive global addresses
  for (int s = threadIdx.x; s < lim; s += 256) {
    const unsigned long long rc = sbuf[s];
    const int b = (int)(rc >> (33 + CB));
    staged[(size_t)(gofs[b] + s)] = rc;
  }
}

// Pass B (R19: scatter-only). Cursors come precomputed from row_start — the
// old per-block hist pass (12.8MB hi-dword reads + 256-wide scan) is gone.
__global__ __launch_bounds__(256) void partB_kernel(
    const int* __restrict__ bucket_start,
    const unsigned long long* __restrict__ staged,
    const int* __restrict__ row_start, int2* __restrict__ edges) {
  __shared__ int cnt[1 << CB];
  const int b  = blockIdx.x;
  const int r0 = b << CB;
  const int rn = min(NN - r0, 1 << CB);
  const int s  = bucket_start[b];
  const int e  = bucket_start[b + 1];
  cnt[threadIdx.x] = ((int)threadIdx.x < rn) ? row_start[r0 + threadIdx.x] : 0;
  __syncthreads();
  // scatter into final CSR order (block-local ~65KB window, L2-hot)
  for (int p = s + threadIdx.x; p < e; p += 256) {
    const unsigned long long rc = staged[p];
    const int r = (int)(rc >> 33);
    const int c = (int)((rc >> 16) & 0x1FFFF);
    const float vv = bf2f((unsigned short)(rc & 0xFFFF));
    const int q = atomicAdd(&cnt[r - r0], 1);
    int2 pk; pk.x = c << 6; pk.y = __float_as_int(vv);  // col*64 pre-scaled
    edges[q] = pk;
  }
}

// ---------------- SpMM1 + BN1 + ReLU: h(bf16) = relu(bn1(A @ h0(fp8))) -------
// R6/R8-proven: quad-edge gathers (16 lanes/edge x 16B), exact trip counts
// (bulk full-16s, 4-wise tail), nt h-store. At the fabric-service roofline.
__global__ __launch_bounds__(256, 8) void spmm1_kernel(
    const unsigned char* __restrict__ h0, const int* __restrict__ row_start,
    const int2* __restrict__ edges,
    const float* __restrict__ gamma, const float* __restrict__ beta,
    const float* __restrict__ mean, const float* __restrict__ var,
    unsigned short* __restrict__ h) {
  const int row  = (blockIdx.x * blockDim.x + threadIdx.x) >> 6;
  const int lane = threadIdx.x & 63;
  const int grp  = lane >> 4;      // 0..3: which edge of the quad
  const int t    = lane & 15;      // sublane: dims [t*16, t*16+16)
  const int t16  = t * 16;
  const int s = row_start[row];
  const int e = row_start[row + 1];
  floatx2 acc[8];
#pragma unroll
  for (int j = 0; j < 8; ++j) acc[j] = floatx2{0.f, 0.f};

  const int ebulk = s + ((e - s) & ~15);
  int p = s;
  for (; p < ebulk; p += 16) {
    unsigned coff[4];
    float    vv4[4];
#pragma unroll
    for (int k = 0; k < 4; ++k) {
      const int2 er = edges[p + k * 4 + grp];
      coff[k] = (unsigned)er.x;                    // col*64
      vv4[k]  = __int_as_float(er.y);
    }
    uint4 gg[4];
#pragma unroll
    for (int k = 0; k < 4; ++k)
      gg[k] = *(const uint4*)(h0 + (size_t)coff[k] * 4 + t16);
#pragma unroll
    for (int k = 0; k < 4; ++k) {
      const floatx2 v2 = {vv4[k], vv4[k]};
      acc[0] += __builtin_amdgcn_cvt_pk_f32_fp8(gg[k].x, false) * v2;
      acc[1] += __builtin_amdgcn_cvt_pk_f32_fp8(gg[k].x, true)  * v2;
      acc[2] += __builtin_amdgcn_cvt_pk_f32_fp8(gg[k].y, false) * v2;
      acc[3] += __builtin_amdgcn_cvt_pk_f32_fp8(gg[k].y, true)  * v2;
      acc[4] += __builtin_amdgcn_cvt_pk_f32_fp8(gg[k].z, false) * v2;
      acc[5] += __builtin_amdgcn_cvt_pk_f32_fp8(gg[k].z, true)  * v2;
      acc[6] += __builtin_amdgcn_cvt_pk_f32_fp8(gg[k].w, false) * v2;
      acc[7] += __builtin_amdgcn_cvt_pk_f32_fp8(gg[k].w, true)  * v2;
    }
  }
  // tail: one quad (4 edges) per iteration, <=3 wasted slots total per row
  for (; p < e; p += 4) {
    const int idx = p + grp;
    const bool valid = idx < e;
    const int2 er = edges[valid ? idx : e - 1];   // e-1 >= s >= 0 since p < e
    const unsigned coff = (unsigned)er.x;
    const float vv = valid ? __int_as_float(er.y) : 0.f;
    const uint4 gg = *(const uint4*)(h0 + (size_t)coff * 4 + t16);
    const floatx2 v2 = {vv, vv};
    acc[0] += __builtin_amdgcn_cvt_pk_f32_fp8(gg.x, false) * v2;
    acc[1] += __builtin_amdgcn_cvt_pk_f32_fp8(gg.x, true)  * v2;
    acc[2] += __builtin_amdgcn_cvt_pk_f32_fp8(gg.y, false) * v2;
    acc[3] += __builtin_amdgcn_cvt_pk_f32_fp8(gg.y, true)  * v2;
    acc[4] += __builtin_amdgcn_cvt_pk_f32_fp8(gg.z, false) * v2;
    acc[5] += __builtin_amdgcn_cvt_pk_f32_fp8(gg.z, true)  * v2;
    acc[6] += __builtin_amdgcn_cvt_pk_f32_fp8(gg.w, false) * v2;
    acc[7] += __builtin_amdgcn_cvt_pk_f32_fp8(gg.w, true)  * v2;
  }
  // combine partials across the 4 lane groups (same dims at lanes t+16k)
#pragma unroll
  for (int j = 0; j < 8; ++j) {
    acc[j][0] += __shfl_xor(acc[j][0], 16);
    acc[j][1] += __shfl_xor(acc[j][1], 16);
  }
#pragma unroll
  for (int j = 0; j < 8; ++j) {
    acc[j][0] += __shfl_xor(acc[j][0], 32);
    acc[j][1] += __shfl_xor(acc[j][1], 32);
  }
  // lane (grp,t) writes dims [t*16 + grp*4, +4)
  floatx2 pa, pb;
  if (grp == 0)      { pa = acc[0]; pb = acc[1]; }
  else if (grp == 1) { pa = acc[2]; pb = acc[3]; }
  else if (grp == 2) { pa = acc[4]; pb = acc[5]; }
  else               { pa = acc[6]; pb = acc[7]; }
  const int d = t16 + grp * 4;
  float4 g  = *(const float4*)(gamma + d);
  float4 b  = *(const float4*)(beta + d);
  float4 m  = *(const float4*)(mean + d);
  float4 vv = *(const float4*)(var + d);
  const unsigned short o0 =
      f2bf(fmaxf(fmaf((pa[0] - m.x) * rsqrtf(vv.x + EPS_BN), g.x, b.x), 0.f));
  const unsigned short o1 =
      f2bf(fmaxf(fmaf((pa[1] - m.y) * rsqrtf(vv.y + EPS_BN), g.y, b.y), 0.f));
  const unsigned short o2 =
      f2bf(fmaxf(fmaf((pb[0] - m.z) * rsqrtf(vv.z + EPS_BN), g.z, b.z), 0.f));
  const unsigned short o3 =
      f2bf(fmaxf(fmaf((pb[1] - m.w) * rsqrtf(vv.w + EPS_BN), g.w, b.w), 0.f));
  const unsigned long long ow =
      (unsigned long long)o0 | ((unsigned long long)o1 << 16) |
      ((unsigned long long)o2 << 32) | ((unsigned long long)o3 << 48);
  __builtin_nontemporal_store(
      ow, (unsigned long long*)(h + (size_t)row * HIDD + d));
}

// ---------------- SpMM2 + BN2: out = bn2(A @ z0(fp8)) ------------------------
// R6/R8-proven exact-trip-count structure; out store non-temporal.
__global__ __launch_bounds__(256, 8) void spmm2_kernel(
    const unsigned char* __restrict__ z0, const int* __restrict__ row_start,
    const int2* __restrict__ edges,
    const float* __restrict__ gamma, const float* __restrict__ beta,
    const float* __restrict__ mean, const float* __restrict__ var,
    float* __restrict__ out) {
  const int row  = (blockIdx.x * blockDim.x + threadIdx.x) >> 6;
  const int lane = threadIdx.x & 63;
  const int grp  = lane >> 4;      // 0..3
  const int t    = lane & 15;      // dims [t*4, t*4+4)
  const int t4   = t * 4;
  const int s = row_start[row];
  const int e = row_start[row + 1];
  floatx2 a01 = {0.f, 0.f};
  floatx2 a23 = {0.f, 0.f};
  const int ebulk = s + ((e - s) & ~15);
  int p = s;
  for (; p < ebulk; p += 16) {
    unsigned coff[4];
    float    vv4[4];
#pragma unroll
    for (int k = 0; k < 4; ++k) {
      const int2 er = edges[p + k * 4 + grp];
      coff[k] = (unsigned)er.x;                    // col*64
      vv4[k]  = __int_as_float(er.y);
    }
    unsigned gg[4];
#pragma unroll
    for (int k = 0; k < 4; ++k)
      gg[k] = *(const unsigned*)(z0 + (size_t)coff[k] + t4);
#pragma unroll
    for (int k = 0; k < 4; ++k) {
      const floatx2 v2 = {vv4[k], vv4[k]};
      a01 += __builtin_amdgcn_cvt_pk_f32_fp8(gg[k], false) * v2;
      a23 += __builtin_amdgcn_cvt_pk_f32_fp8(gg[k], true)  * v2;
    }
  }
  for (; p < e; p += 4) {
    const int idx = p + grp;
    const bool valid = idx < e;
    const int2 er = edges[valid ? idx : e - 1];
    const unsigned coff = (unsigned)er.x;
    const float vvs = valid ? __int_as_float(er.y) : 0.f;
    const unsigned gg = *(const unsigned*)(z0 + (size_t)coff + t4);
    const floatx2 v2 = {vvs, vvs};
    a01 += __builtin_amdgcn_cvt_pk_f32_fp8(gg, false) * v2;
    a23 += __builtin_amdgcn_cvt_pk_f32_fp8(gg, true)  * v2;
  }
  a01[0] += __shfl_xor(a01[0], 16); a01[1] += __shfl_xor(a01[1], 16);
  a23[0] += __shfl_xor(a23[0], 16); a23[1] += __shfl_xor(a23[1], 16);
  a01[0] += __shfl_xor(a01[0], 32); a01[1] += __shfl_xor(a01[1], 32);
  a23[0] += __shfl_xor(a23[0], 32); a23[1] += __shfl_xor(a23[1], 32);
  // lane (grp,t) writes dim t*4 + grp
  float av;
  if (grp == 0)      av = a01[0];
  else if (grp == 1) av = a01[1];
  else if (grp == 2) av = a23[0];
  else               av = a23[1];
  const int d = t4 + grp;
  const float r = fmaf((av - mean[d]) * rsqrtf(var[d] + EPS_BN), gamma[d],
                       beta[d]);
  __builtin_nontemporal_store(r, out + (size_t)row * EMBD + d);
}

extern "C" void kernel_launch(void* const* d_in, const int* in_sizes, int n_in,
                              void* d_out, int out_size, void* d_ws, size_t ws_size,
                              hipStream_t stream) {
  const float* x        = (const float*)d_in[0];
  const int*   edge_row = (const int*)d_in[1];
  const int*   edge_col = (const int*)d_in[2];
  const float* edge_val = (const float*)d_in[3];
  const float* w1       = (const float*)d_in[4];
  const float* w2       = (const float*)d_in[5];
  const float* gamma1   = (const float*)d_in[6];
  const float* beta1    = (const float*)d_in[7];
  const float* mean1    = (const float*)d_in[8];
  const float* var1     = (const float*)d_in[9];
  const float* gamma2   = (const float*)d_in[10];
  const float* beta2    = (const float*)d_in[11];
  const float* mean2    = (const float*)d_in[12];
  const float* var2     = (const float*)d_in[13];
  float* out = (float*)d_out;

  // Workspace layout (256B aligned). Total ~111 MB.
  char* ws = (char*)d_ws;
  size_t off = 0;
  auto alloc = [&](size_t bytes) -> void* {
    void* p = ws + off;
    off = (off + bytes + 255) & ~(size_t)255;
    return p;
  };
  unsigned char*  h0  = (unsigned char*)alloc((size_t)NN * HIDD);       // 25.6MB fp8
  unsigned short* h   = (unsigned short*)alloc((size_t)NN * HIDD * 2);  // 51.2MB bf16
  // staged records alias h: 25.6MB, dead before spmm1 writes h
  unsigned long long* staged = (unsigned long long*)h;
  unsigned char*  z0  = (unsigned char*)alloc((size_t)NN * EMBD);       // 6.4MB fp8
  unsigned short* w1s = (unsigned short*)alloc((size_t)IND * HIDD * 2);
  unsigned short* w2s = (unsigned short*)alloc((size_t)HIDD * EMBD * 2);
  int*   row_start    = (int*)alloc((size_t)(NN + 1) * 4);
  int*   cnt          = (int*)alloc((size_t)NN * 4);                    // 400KB
  int*   excl         = (int*)alloc((size_t)NN * 4);                    // 400KB
  int*   btot         = (int*)alloc((size_t)NB * 4);
  int*   bcur         = (int*)alloc((size_t)NB * 16 * 4);               // 25KB padded
  int*   bucket_start = (int*)alloc((size_t)(NB + 1) * 4);
  int2*  edges        = (int2*)alloc((size_t)EE * 8);                   // 25.6MB

  // weight swizzles (independent of CSR build)
  swz_w1_kernel<<<8192 / 256, 256, 0, stream>>>(w1, w1s);
  swz_w2_kernel<<<2048 / 256, 256, 0, stream>>>(w2, w2s);

  // CSR build: row hist -> bucket scans -> row_start -> LDS counting-sort
  // partition (A) -> scatter-only (B)
  hipMemsetAsync(cnt, 0, (size_t)NN * 4, stream);
  histr_kernel<<<(EE + 255) / 256, 256, 0, stream>>>(edge_row, cnt);
  scanA_kernel<<<NB, 256, 0, stream>>>(cnt, excl, btot);
  scanB_kernel<<<1, 512, 0, stream>>>(btot, bucket_start, bcur);
  fin_kernel<<<NB, 256, 0, stream>>>(bucket_start, excl, row_start);
  partA_kernel<<<NCHUNK, 256, 0, stream>>>(
      edge_row, edge_col, edge_val, bcur, staged);
  partB_kernel<<<NB, 256, 0, stream>>>(bucket_start, staged, row_start, edges);

  // Layer 1: h0 = fp8(bf16(x) @ w1) ; h = bf16(relu(bn1(A @ h0)))
  gemm1_mfma<<<GGRID, 512, 0, stream>>>(x, w1s, h0);
  spmm1_kernel<<<NN / 4, 256, 0, stream>>>(h0, row_start, edges,
                                           gamma1, beta1, mean1, var1, h);
  // Layer 2: z0 = fp8(h @ w2) ; out = bn2(A @ z0)
  gemm2_mfma<<<GGRID, 256, 0, stream>>>(h, w2s, z0);
  spmm2_kernel<<<NN / 4, 256, 0, stream>>>(z0, row_start, edges,
                                           gamma2, beta2, mean2, var2, out);
}

// Round 15
// 509.201 us; speedup vs baseline: 1.7360x; 1.1984x over previous
//
#include <hip/hip_runtime.h>
#include <hip/hip_bf16.h>

// Problem constants (from reference)
constexpr int NN   = 100000;   // nodes
constexpr int IND  = 256;      // input dim
constexpr int HIDD = 256;      // hidden dim
constexpr int EMBD = 64;       // embedding dim
constexpr int EE   = 3200000;  // edges
// CSR coarse partition: bucket = row >> CB (256 rows per bucket)
constexpr int CB    = 8;
constexpr int NB    = ((NN - 1) >> CB) + 1;   // 391
constexpr int NBP   = 512;                    // padded for LDS scan
constexpr int CHUNK = 4096;                   // edges per partA block
constexpr int EPT   = CHUNK / 256;            // 16 edges per thread
constexpr int NCHUNK = (EE + CHUNK - 1) / CHUNK;  // 782
// LEDGER of refuted directions (do not retry):
//  1) R13 direct-scatter CSR: 8B random stores -> 8x write-allocate (790us).
//  2) R15-R17 gemm2-into-spmm1 fusion: 567/521/534 vs 510 unfused.
//  3) R18 column-sliced spmm1: line granularity + 8x XCD fill replication +
//     8x edge re-read -> 884us. spmm1 is fabric-service bound (~410MB @
//     ~3.8TB/s); 4 gather formulations within 8% -> STRUCTURAL CEILING.
//  4) R19 row-histogram CSR: 3.2M random global atomics -> line ping-pong,
//     WRITE 99.8MB for a 400KB array, 129us (vs histb <10us). Random
//     sub-line global ops (stores OR atomics) always lose ~8x; the
//     LDS-aggregate->few-atomics pattern (histb/partA) is load-bearing.
// R21 (this file): exact revert to R6 — best measured config (509.9us).
constexpr int GMT    = 8;
constexpr int GROWS  = GMT * 16;                        // 128
constexpr int GGRID  = (NN + GROWS - 1) / GROWS;        // 782
constexpr int APITCH = 264;  // bf16 elems per row (256 + 8 pad = 528B, bank-balanced)
#define EPS_BN 1e-3f

typedef short  short8  __attribute__((ext_vector_type(8)));
typedef float  floatx4 __attribute__((ext_vector_type(4)));
typedef float  floatx2 __attribute__((ext_vector_type(2)));

static __device__ __forceinline__ unsigned short f2bf(float f) {
  __hip_bfloat16 b = __float2bfloat16(f);
  union { __hip_bfloat16 b; unsigned short u; } cv;
  cv.b = b;
  return cv.u;
}
static __device__ __forceinline__ float bf2f(unsigned short u) {
  return __uint_as_float(((unsigned)u) << 16);
}
static __device__ __forceinline__ unsigned char f2fp8(float f) {
  // v_cvt_pk_fp8_f32: OCP e4m3fn on gfx950
  return (unsigned char)__builtin_amdgcn_cvt_pk_fp8_f32(f, f, 0, false);
}

// ---- swizzle weights into MFMA B-fragment layout -----------------------------
__global__ __launch_bounds__(256) void swz_w1_kernel(
    const float* __restrict__ w1, unsigned short* __restrict__ w1s) {
  const int t = blockIdx.x * blockDim.x + threadIdx.x;  // 8192 threads
  const int lane = t & 63;
  const int f = t >> 6;          // 0..127
  const int kt = f >> 4;         // 0..7
  const int nt = f & 15;         // 0..15
  const int n = nt * 16 + (lane & 15);
#pragma unroll
  for (int j = 0; j < 8; ++j) {
    const int k = kt * 32 + (lane >> 4) * 8 + j;
    w1s[(size_t)(f * 64 + lane) * 8 + j] = f2bf(w1[k * HIDD + n]);
  }
}

__global__ __launch_bounds__(256) void swz_w2_kernel(
    const float* __restrict__ w2, unsigned short* __restrict__ w2s) {
  const int t = blockIdx.x * blockDim.x + threadIdx.x;  // 2048 threads
  const int lane = t & 63;
  const int f = t >> 6;          // 0..31
  const int kt = f >> 2;         // 0..7
  const int nt = f & 3;          // 0..3
  const int n = nt * 16 + (lane & 15);
#pragma unroll
  for (int j = 0; j < 8; ++j) {
    const int k = kt * 32 + (lane >> 4) * 8 + j;
    w2s[(size_t)(f * 64 + lane) * 8 + j] = f2bf(w2[k * EMBD + n]);
  }
}

// ---------------- GEMM1 (MFMA): h0(fp8) = bf16(x) @ w1 -----------------------
// 782 blocks x 8 m-tiles. A tile (16x256 f32) reg-staged -> bf16 LDS (dbuf),
// one barrier per m-tile. Each x byte fetched exactly once per block.
__global__ __launch_bounds__(512) void gemm1_mfma(
    const float* __restrict__ x, const unsigned short* __restrict__ w1s,
    unsigned char* __restrict__ h0) {
  __shared__ unsigned short sa[2][16][APITCH];  // 16.9 KB
  const int tid  = threadIdx.x;
  const int lane = tid & 63;
  const int wave = tid >> 6;   // 0..7
  const int quad = lane >> 4;
  const int l15  = lane & 15;
  // B fragments: wave covers cols [wave*32, wave*32+32) as 2 n-tiles of 16
  const short8* w1v = (const short8*)w1s;
  short8 bf[2][8];
#pragma unroll
  for (int nt2 = 0; nt2 < 2; ++nt2)
#pragma unroll
    for (int kt = 0; kt < 8; ++kt)
      bf[nt2][kt] = w1v[(size_t)(kt * 16 + wave * 2 + nt2) * 64 + lane];

  const int mbase = blockIdx.x * GROWS;
  // staging: thread t covers floats [t*8, t*8+8) of the 16x256 tile
  const int srow = tid >> 5;          // 0..15
  const int scol = (tid & 31) * 8;    // float col, 32B per thread

  auto srcp = [&](int mt) -> const float* {
    int r = mbase + mt * 16 + srow;
    if (r >= NN) r = NN - 1;          // clamp (stores are guarded)
    return x + (size_t)r * IND + scol;
  };

  // prologue: stage tile 0 into buf 0
  {
    const float* p = srcp(0);
    float4 g0 = *(const float4*)(p);
    float4 g1 = *(const float4*)(p + 4);
    short8 s;
    s[0] = (short)f2bf(g0.x); s[1] = (short)f2bf(g0.y);
    s[2] = (short)f2bf(g0.z); s[3] = (short)f2bf(g0.w);
    s[4] = (short)f2bf(g1.x); s[5] = (short)f2bf(g1.y);
    s[6] = (short)f2bf(g1.z); s[7] = (short)f2bf(g1.w);
    *(short8*)&sa[0][srow][(tid & 31) * 8] = s;
  }

#pragma unroll
  for (int mt = 0; mt < GMT; ++mt) {
    const int cur = mt & 1;
    // issue next-tile global loads (in flight across the MFMA phase)
    float4 g0, g1;
    if (mt + 1 < GMT) {
      const float* p = srcp(mt + 1);
      g0 = *(const float4*)(p);
      g1 = *(const float4*)(p + 4);
    }
    __syncthreads();  // buf[cur] writes visible; prev reads of buf[cur^1] done
    // A-frags from LDS + MFMA
    floatx4 c0 = {0.f, 0.f, 0.f, 0.f};
    floatx4 c1 = {0.f, 0.f, 0.f, 0.f};
#pragma unroll
    for (int kt = 0; kt < 8; ++kt) {
      short8 a = *(const short8*)&sa[cur][l15][quad * 8 + kt * 32];
      c0 = __builtin_amdgcn_mfma_f32_16x16x32_bf16(a, bf[0][kt], c0, 0, 0, 0);
      c1 = __builtin_amdgcn_mfma_f32_16x16x32_bf16(a, bf[1][kt], c1, 0, 0, 0);
    }
    // C/D layout: col = lane&15, row = quad*4 + reg  [verified m89/m91]
    const int m0 = mbase + mt * 16;
    if (m0 < NN) {  // NN % 16 == 0 -> whole m-tile valid or none
      unsigned char* o = h0 + (size_t)(m0 + quad * 4) * HIDD + wave * 32 + l15;
#pragma unroll
      for (int r = 0; r < 4; ++r) {
        o[(size_t)r * HIDD]      = f2fp8(c0[r]);
        o[(size_t)r * HIDD + 16] = f2fp8(c1[r]);
      }
    }
    // convert staged regs -> write other buffer (read next iter after barrier)
    if (mt + 1 < GMT) {
      short8 s;
      s[0] = (short)f2bf(g0.x); s[1] = (short)f2bf(g0.y);
      s[2] = (short)f2bf(g0.z); s[3] = (short)f2bf(g0.w);
      s[4] = (short)f2bf(g1.x); s[5] = (short)f2bf(g1.y);
      s[6] = (short)f2bf(g1.z); s[7] = (short)f2bf(g1.w);
      *(short8*)&sa[cur ^ 1][srow][(tid & 31) * 8] = s;
    }
  }
}

// ---------------- GEMM2 (MFMA): z0(fp8) = h(bf16) @ w2 -----------------------
// Same LDS-dbuf template; h already bf16 so staging is a straight copy.
__global__ __launch_bounds__(256) void gemm2_mfma(
    const unsigned short* __restrict__ hb, const unsigned short* __restrict__ w2s,
    unsigned char* __restrict__ z0) {
  __shared__ unsigned short sa[2][16][APITCH];  // 16.9 KB
  const int tid  = threadIdx.x;
  const int lane = tid & 63;
  const int wave = tid >> 6;   // 0..3
  const int quad = lane >> 4;
  const int l15  = lane & 15;
  const short8* w2v = (const short8*)w2s;
  short8 bf[8];
#pragma unroll
  for (int kt = 0; kt < 8; ++kt)
    bf[kt] = w2v[(size_t)(kt * 4 + wave) * 64 + lane];

  const int mbase = blockIdx.x * GROWS;
  // staging: thread t covers shorts [t*16, t*16+16) of the 16x256 bf16 tile
  const int srow = tid >> 4;          // 0..15
  const int scol = (tid & 15) * 16;   // short col, 32B per thread

  auto srcp = [&](int mt) -> const unsigned short* {
    int r = mbase + mt * 16 + srow;
    if (r >= NN) r = NN - 1;
    return hb + (size_t)r * HIDD + scol;
  };

  {
    const unsigned short* p = srcp(0);
    short8 g0 = *(const short8*)(p);
    short8 g1 = *(const short8*)(p + 8);
    *(short8*)&sa[0][srow][scol]     = g0;
    *(short8*)&sa[0][srow][scol + 8] = g1;
  }

#pragma unroll
  for (int mt = 0; mt < GMT; ++mt) {
    const int cur = mt & 1;
    short8 g0, g1;
    if (mt + 1 < GMT) {
      const unsigned short* p = srcp(mt + 1);
      g0 = *(const short8*)(p);
      g1 = *(const short8*)(p + 8);
    }
    __syncthreads();
    floatx4 c = {0.f, 0.f, 0.f, 0.f};
#pragma unroll
    for (int kt = 0; kt < 8; ++kt) {
      short8 a = *(const short8*)&sa[cur][l15][quad * 8 + kt * 32];
      c = __builtin_amdgcn_mfma_f32_16x16x32_bf16(a, bf[kt], c, 0, 0, 0);
    }
    const int m0 = mbase + mt * 16;
    if (m0 < NN) {
      unsigned char* o = z0 + (size_t)(m0 + quad * 4) * EMBD + wave * 16 + l15;
#pragma unroll
      for (int r = 0; r < 4; ++r) o[(size_t)r * EMBD] = f2fp8(c[r]);
    }
    if (mt + 1 < GMT) {
      *(short8*)&sa[cur ^ 1][srow][scol]     = g0;
      *(short8*)&sa[cur ^ 1][srow][scol + 8] = g1;
    }
  }
}

// ---------------- CSR build --------------------------------------------------
// Bucket-level histogram: LDS counters per chunk, <=NB global atomics/chunk.
__global__ __launch_bounds__(256) void histb_kernel(
    const int* __restrict__ row, int* __restrict__ bcnt) {
  __shared__ int lcnt[NB];
  for (int i = threadIdx.x; i < NB; i += 256) lcnt[i] = 0;
  __syncthreads();
  const int base = blockIdx.x * CHUNK;
  const int lim  = min(EE - base, CHUNK);
  for (int i = threadIdx.x; i < lim; i += 256)
    atomicAdd(&lcnt[row[base + i] >> CB], 1);
  __syncthreads();
  for (int i = threadIdx.x; i < NB; i += 256) {
    const int c = lcnt[i];
    if (c) atomicAdd(&bcnt[i * 16], c);
  }
}

// Scan 391 bucket counts -> bucket_start (compact) + bcur (padded cursors)
__global__ __launch_bounds__(512) void bscan_kernel(
    const int* __restrict__ bcnt, int* __restrict__ bucket_start,
    int* __restrict__ bcur) {
  __shared__ int lds[512];
  int v = (threadIdx.x < NB) ? bcnt[threadIdx.x * 16] : 0;
  lds[threadIdx.x] = v;
  for (int off = 1; off < 512; off <<= 1) {
    __syncthreads();
    int t = (threadIdx.x >= off) ? lds[threadIdx.x - off] : 0;
    __syncthreads();
    lds[threadIdx.x] += t;
  }
  __syncthreads();
  if (threadIdx.x < NB) {
    const int excl = lds[threadIdx.x] - v;
    bucket_start[threadIdx.x] = excl;
    bcur[threadIdx.x * 16] = excl;
  }
  if (threadIdx.x == 0) bucket_start[NB] = EE;
}

// Pass A: LDS counting-sort each 4096-edge chunk by coarse bucket, then flush
// piecewise-contiguous runs with ONE global atomic per (block,bucket).
// Record packs (row:17 | col:17 | val_bf16:16) into 8B.
__global__ __launch_bounds__(256) void partA_kernel(
    const int* __restrict__ row, const int* __restrict__ col,
    const float* __restrict__ val, int* __restrict__ bcur,
    unsigned long long* __restrict__ staged) {
  __shared__ unsigned long long sbuf[CHUNK];  // 32 KB
  __shared__ int cnt[NBP];
  __shared__ int scn[NBP];
  __shared__ int cur[NB];
  __shared__ int gofs[NB];
  const int base = blockIdx.x * CHUNK;
  const int lim  = min(EE - base, CHUNK);
  for (int i = threadIdx.x; i < NBP; i += 256) cnt[i] = 0;
  __syncthreads();
  // load + histogram (records kept in registers)
  unsigned long long rec[EPT];
  int bkt[EPT];
#pragma unroll
  for (int j = 0; j < EPT; ++j) {
    const int idx = threadIdx.x + j * 256;
    bkt[j] = -1;
    if (idx < lim) {
      const int e = base + idx;
      const int r = row[e];
      const int c = col[e];
      const unsigned short v = f2bf(val[e]);
      rec[j] = ((unsigned long long)r << 33) | ((unsigned long long)c << 16) | v;
      bkt[j] = r >> CB;
      atomicAdd(&cnt[bkt[j]], 1);
    }
  }
  __syncthreads();
  // inclusive scan of cnt -> scn (512 entries, 2 per thread)
  for (int i = threadIdx.x; i < NBP; i += 256) scn[i] = cnt[i];
  __syncthreads();
  for (int off = 1; off < NBP; off <<= 1) {
    const int i0 = threadIdx.x, i1 = threadIdx.x + 256;
    const int t0 = (i0 >= off) ? scn[i0 - off] : 0;
    const int t1 = (i1 >= off) ? scn[i1 - off] : 0;
    __syncthreads();
    scn[i0] += t0;
    scn[i1] += t1;
    __syncthreads();
  }
  // placement cursors = exclusive start
  for (int b = threadIdx.x; b < NB; b += 256) cur[b] = scn[b] - cnt[b];
  __syncthreads();
  // reorder into LDS (no line granularity in LDS -> scatter is fine)
#pragma unroll
  for (int j = 0; j < EPT; ++j)
    if (bkt[j] >= 0) {
      const int p = atomicAdd(&cur[bkt[j]], 1);
      sbuf[p] = rec[j];
    }
  __syncthreads();
  // reserve global ranges: one atomic per non-empty bucket
  for (int b = threadIdx.x; b < NB; b += 256) {
    const int c = cnt[b];
    const int g = (c > 0) ? atomicAdd(&bcur[b * 16], c) : 0;
    gofs[b] = g - (scn[b] - c);  // out = gofs[b] + local_slot
  }
  __syncthreads();
  // flush: consecutive slots of a bucket -> consecutive global addresses
  for (int s = threadIdx.x; s < lim; s += 256) {
    const unsigned long long rc = sbuf[s];
    const int b = (int)(rc >> (33 + CB));
    staged[(size_t)(gofs[b] + s)] = rc;
  }
}

// Pass B: one block per coarse bucket (256 rows). Pass 1 histograms rows
// (high-dword reads) -> LDS scan -> writes row_start + cursors. Pass 2
// scatters records into the block-local ~65KB window (L2-hot on re-read).
__global__ __launch_bounds__(256) void partB_kernel(
    const int* __restrict__ bucket_start,
    const unsigned long long* __restrict__ staged,
    int2* __restrict__ edges, int* __restrict__ row_start) {
  __shared__ int cnt[1 << CB];
  __shared__ int ofs[1 << CB];
  const int b  = blockIdx.x;
  const int r0 = b << CB;
  const int rn = min(NN - r0, 1 << CB);
  const int s  = bucket_start[b];
  const int e  = bucket_start[b + 1];
  cnt[threadIdx.x] = 0;
  __syncthreads();
  // pass 1: row histogram (read only the high dword of each record)
  const unsigned* hi = (const unsigned*)staged;
  for (int p = s + threadIdx.x; p < e; p += 256) {
    const unsigned hw = hi[2 * p + 1];
    const int r = (int)((hw >> 1) & 0x1FFFF);
    atomicAdd(&cnt[r - r0], 1);
  }
  __syncthreads();
  // exclusive scan of 256 bins
  const int v = cnt[threadIdx.x];
  ofs[threadIdx.x] = v;
  for (int off = 1; off < 256; off <<= 1) {
    __syncthreads();
    const int t = (threadIdx.x >= off) ? ofs[threadIdx.x - off] : 0;
    __syncthreads();
    ofs[threadIdx.x] += t;
  }
  __syncthreads();
  const int excl = ofs[threadIdx.x] - v;
  if ((int)threadIdx.x < rn) row_start[r0 + threadIdx.x] = s + excl;
  if (b == NB - 1 && threadIdx.x == 0) row_start[NN] = e;
  __syncthreads();
  cnt[threadIdx.x] = s + excl;  // reuse as cursors
  __syncthreads();
  // pass 2: scatter into final CSR order
  for (int p = s + threadIdx.x; p < e; p += 256) {
    const unsigned long long rc = staged[p];
    const int r = (int)(rc >> 33);
    const int c = (int)((rc >> 16) & 0x1FFFF);
    const float vv = bf2f((unsigned short)(rc & 0xFFFF));
    const int q = atomicAdd(&cnt[r - r0], 1);
    int2 pk; pk.x = c << 6; pk.y = __float_as_int(vv);  // col*64 pre-scaled
    edges[q] = pk;
  }
}

// ---------------- SpMM1 + BN1 + ReLU: h(bf16) = relu(bn1(A @ h0(fp8))) -------
// Quad-edge gathers (16 lanes/edge x 16B), exact trip counts (bulk full-16s,
// 4-wise tail). At the gather-fabric service roofline (see ledger #3).
__global__ __launch_bounds__(256, 8) void spmm1_kernel(
    const unsigned char* __restrict__ h0, const int* __restrict__ row_start,
    const int2* __restrict__ edges,
    const float* __restrict__ gamma, const float* __restrict__ beta,
    const float* __restrict__ mean, const float* __restrict__ var,
    unsigned short* __restrict__ h) {
  const int row  = (blockIdx.x * blockDim.x + threadIdx.x) >> 6;
  const int lane = threadIdx.x & 63;
  const int grp  = lane >> 4;      // 0..3: which edge of the quad
  const int t    = lane & 15;      // sublane: dims [t*16, t*16+16)
  const int t16  = t * 16;
  const int s = row_start[row];
  const int e = row_start[row + 1];
  floatx2 acc[8];
#pragma unroll
  for (int j = 0; j < 8; ++j) acc[j] = floatx2{0.f, 0.f};

  const int ebulk = s + ((e - s) & ~15);
  int p = s;
  for (; p < ebulk; p += 16) {
    unsigned coff[4];
    float    vv4[4];
#pragma unroll
    for (int k = 0; k < 4; ++k) {
      const int2 er = edges[p + k * 4 + grp];
      coff[k] = (unsigned)er.x;                    // col*64
      vv4[k]  = __int_as_float(er.y);
    }
    uint4 gg[4];
#pragma unroll
    for (int k = 0; k < 4; ++k)
      gg[k] = *(const uint4*)(h0 + (size_t)coff[k] * 4 + t16);
#pragma unroll
    for (int k = 0; k < 4; ++k) {
      const floatx2 v2 = {vv4[k], vv4[k]};
      acc[0] += __builtin_amdgcn_cvt_pk_f32_fp8(gg[k].x, false) * v2;
      acc[1] += __builtin_amdgcn_cvt_pk_f32_fp8(gg[k].x, true)  * v2;
      acc[2] += __builtin_amdgcn_cvt_pk_f32_fp8(gg[k].y, false) * v2;
      acc[3] += __builtin_amdgcn_cvt_pk_f32_fp8(gg[k].y, true)  * v2;
      acc[4] += __builtin_amdgcn_cvt_pk_f32_fp8(gg[k].z, false) * v2;
      acc[5] += __builtin_amdgcn_cvt_pk_f32_fp8(gg[k].z, true)  * v2;
      acc[6] += __builtin_amdgcn_cvt_pk_f32_fp8(gg[k].w, false) * v2;
      acc[7] += __builtin_amdgcn_cvt_pk_f32_fp8(gg[k].w, true)  * v2;
    }
  }
  // tail: one quad (4 edges) per iteration, <=3 wasted slots total per row
  for (; p < e; p += 4) {
    const int idx = p + grp;
    const bool valid = idx < e;
    const int2 er = edges[valid ? idx : e - 1];   // e-1 >= s >= 0 since p < e
    const unsigned coff = (unsigned)er.x;
    const float vv = valid ? __int_as_float(er.y) : 0.f;
    const uint4 gg = *(const uint4*)(h0 + (size_t)coff * 4 + t16);
    const floatx2 v2 = {vv, vv};
    acc[0] += __builtin_amdgcn_cvt_pk_f32_fp8(gg.x, false) * v2;
    acc[1] += __builtin_amdgcn_cvt_pk_f32_fp8(gg.x, true)  * v2;
    acc[2] += __builtin_amdgcn_cvt_pk_f32_fp8(gg.y, false) * v2;
    acc[3] += __builtin_amdgcn_cvt_pk_f32_fp8(gg.y, true)  * v2;
    acc[4] += __builtin_amdgcn_cvt_pk_f32_fp8(gg.z, false) * v2;
    acc[5] += __builtin_amdgcn_cvt_pk_f32_fp8(gg.z, true)  * v2;
    acc[6] += __builtin_amdgcn_cvt_pk_f32_fp8(gg.w, false) * v2;
    acc[7] += __builtin_amdgcn_cvt_pk_f32_fp8(gg.w, true)  * v2;
  }
  // combine partials across the 4 lane groups (same dims at lanes t+16k)
#pragma unroll
  for (int j = 0; j < 8; ++j) {
    acc[j][0] += __shfl_xor(acc[j][0], 16);
    acc[j][1] += __shfl_xor(acc[j][1], 16);
  }
#pragma unroll
  for (int j = 0; j < 8; ++j) {
    acc[j][0] += __shfl_xor(acc[j][0], 32);
    acc[j][1] += __shfl_xor(acc[j][1], 32);
  }
  // lane (grp,t) writes dims [t*16 + grp*4, +4)
  floatx2 pa, pb;
  if (grp == 0)      { pa = acc[0]; pb = acc[1]; }
  else if (grp == 1) { pa = acc[2]; pb = acc[3]; }
  else if (grp == 2) { pa = acc[4]; pb = acc[5]; }
  else               { pa = acc[6]; pb = acc[7]; }
  const int d = t16 + grp * 4;
  float4 g  = *(const float4*)(gamma + d);
  float4 b  = *(const float4*)(beta + d);
  float4 m  = *(const float4*)(mean + d);
  float4 vv = *(const float4*)(var + d);
  ushort4 o;
  o.x = f2bf(fmaxf(fmaf((pa[0] - m.x) * rsqrtf(vv.x + EPS_BN), g.x, b.x), 0.f));
  o.y = f2bf(fmaxf(fmaf((pa[1] - m.y) * rsqrtf(vv.y + EPS_BN), g.y, b.y), 0.f));
  o.z = f2bf(fmaxf(fmaf((pb[0] - m.z) * rsqrtf(vv.z + EPS_BN), g.z, b.z), 0.f));
  o.w = f2bf(fmaxf(fmaf((pb[1] - m.w) * rsqrtf(vv.w + EPS_BN), g.w, b.w), 0.f));
  *(ushort4*)(h + (size_t)row * HIDD + d) = o;
}

// ---------------- SpMM2 + BN2: out = bn2(A @ z0(fp8)) ------------------------
// Same exact-trip-count structure: bulk full-16s, 4-wise tail.
__global__ __launch_bounds__(256, 8) void spmm2_kernel(
    const unsigned char* __restrict__ z0, const int* __restrict__ row_start,
    const int2* __restrict__ edges,
    const float* __restrict__ gamma, const float* __restrict__ beta,
    const float* __restrict__ mean, const float* __restrict__ var,
    float* __restrict__ out) {
  const int row  = (blockIdx.x * blockDim.x + threadIdx.x) >> 6;
  const int lane = threadIdx.x & 63;
  const int grp  = lane >> 4;      // 0..3
  const int t    = lane & 15;      // dims [t*4, t*4+4)
  const int t4   = t * 4;
  const int s = row_start[row];
  const int e = row_start[row + 1];
  floatx2 a01 = {0.f, 0.f};
  floatx2 a23 = {0.f, 0.f};
  const int ebulk = s + ((e - s) & ~15);
  int p = s;
  for (; p < ebulk; p += 16) {
    unsigned coff[4];
    float    vv4[4];
#pragma unroll
    for (int k = 0; k < 4; ++k) {
      const int2 er = edges[p + k * 4 + grp];
      coff[k] = (unsigned)er.x;                    // col*64
      vv4[k]  = __int_as_float(er.y);
    }
    unsigned gg[4];
#pragma unroll
    for (int k = 0; k < 4; ++k)
      gg[k] = *(const unsigned*)(z0 + (size_t)coff[k] + t4);
#pragma unroll
    for (int k = 0; k < 4; ++k) {
      const floatx2 v2 = {vv4[k], vv4[k]};
      a01 += __builtin_amdgcn_cvt_pk_f32_fp8(gg[k], false) * v2;
      a23 += __builtin_amdgcn_cvt_pk_f32_fp8(gg[k], true)  * v2;
    }
  }
  for (; p < e; p += 4) {
    const int idx = p + grp;
    const bool valid = idx < e;
    const int2 er = edges[valid ? idx : e - 1];
    const unsigned coff = (unsigned)er.x;
    const float vvs = valid ? __int_as_float(er.y) : 0.f;
    const unsigned gg = *(const unsigned*)(z0 + (size_t)coff + t4);
    const floatx2 v2 = {vvs, vvs};
    a01 += __builtin_amdgcn_cvt_pk_f32_fp8(gg, false) * v2;
    a23 += __builtin_amdgcn_cvt_pk_f32_fp8(gg, true)  * v2;
  }
  a01[0] += __shfl_xor(a01[0], 16); a01[1] += __shfl_xor(a01[1], 16);
  a23[0] += __shfl_xor(a23[0], 16); a23[1] += __shfl_xor(a23[1], 16);
  a01[0] += __shfl_xor(a01[0], 32); a01[1] += __shfl_xor(a01[1], 32);
  a23[0] += __shfl_xor(a23[0], 32); a23[1] += __shfl_xor(a23[1], 32);
  // lane (grp,t) writes dim t*4 + grp
  float av;
  if (grp == 0)      av = a01[0];
  else if (grp == 1) av = a01[1];
  else if (grp == 2) av = a23[0];
  else               av = a23[1];
  const int d = t4 + grp;
  const float r = fmaf((av - mean[d]) * rsqrtf(var[d] + EPS_BN), gamma[d],
                       beta[d]);
  out[(size_t)row * EMBD + d] = r;
}

extern "C" void kernel_launch(void* const* d_in, const int* in_sizes, int n_in,
                              void* d_out, int out_size, void* d_ws, size_t ws_size,
                              hipStream_t stream) {
  const float* x        = (const float*)d_in[0];
  const int*   edge_row = (const int*)d_in[1];
  const int*   edge_col = (const int*)d_in[2];
  const float* edge_val = (const float*)d_in[3];
  const float* w1       = (const float*)d_in[4];
  const float* w2       = (const float*)d_in[5];
  const float* gamma1   = (const float*)d_in[6];
  const float* beta1    = (const float*)d_in[7];
  const float* mean1    = (const float*)d_in[8];
  const float* var1     = (const float*)d_in[9];
  const float* gamma2   = (const float*)d_in[10];
  const float* beta2    = (const float*)d_in[11];
  const float* mean2    = (const float*)d_in[12];
  const float* var2     = (const float*)d_in[13];
  float* out = (float*)d_out;

  // Workspace layout (256B aligned). Total ~110 MB.
  char* ws = (char*)d_ws;
  size_t off = 0;
  auto alloc = [&](size_t bytes) -> void* {
    void* p = ws + off;
    off = (off + bytes + 255) & ~(size_t)255;
    return p;
  };
  unsigned char*  h0  = (unsigned char*)alloc((size_t)NN * HIDD);       // 25.6MB fp8
  unsigned short* h   = (unsigned short*)alloc((size_t)NN * HIDD * 2);  // 51.2MB bf16
  // staged records alias h: 25.6MB, dead before spmm1 writes h
  unsigned long long* staged = (unsigned long long*)h;
  unsigned char*  z0  = (unsigned char*)alloc((size_t)NN * EMBD);       // 6.4MB fp8
  unsigned short* w1s = (unsigned short*)alloc((size_t)IND * HIDD * 2);
  unsigned short* w2s = (unsigned short*)alloc((size_t)HIDD * EMBD * 2);
  int*   row_start    = (int*)alloc((size_t)(NN + 1) * 4);
  int*   bcnt         = (int*)alloc((size_t)NB * 16 * 4);               // 25KB padded
  int*   bcur         = (int*)alloc((size_t)NB * 16 * 4);               // 25KB padded
  int*   bucket_start = (int*)alloc((size_t)(NB + 1) * 4);
  int2*  edges        = (int2*)alloc((size_t)EE * 8);                   // 25.6MB

  // weight swizzles (independent of CSR build)
  swz_w1_kernel<<<8192 / 256, 256, 0, stream>>>(w1, w1s);
  swz_w2_kernel<<<2048 / 256, 256, 0, stream>>>(w2, w2s);

  // CSR build: bucket hist -> bucket scan -> LDS counting-sort partition (A)
  //            -> per-bucket row_start + sort (B)
  hipMemsetAsync(bcnt, 0, (size_t)NB * 16 * 4, stream);
  histb_kernel<<<NCHUNK, 256, 0, stream>>>(edge_row, bcnt);
  bscan_kernel<<<1, 512, 0, stream>>>(bcnt, bucket_start, bcur);
  partA_kernel<<<NCHUNK, 256, 0, stream>>>(
      edge_row, edge_col, edge_val, bcur, staged);
  partB_kernel<<<NB, 256, 0, stream>>>(bucket_start, staged, edges, row_start);

  // Layer 1: h0 = fp8(bf16(x) @ w1) ; h = bf16(relu(bn1(A @ h0)))
  gemm1_mfma<<<GGRID, 512, 0, stream>>>(x, w1s, h0);
  spmm1_kernel<<<NN / 4, 256, 0, stream>>>(h0, row_start, edges,
                                           gamma1, beta1, mean1, var1, h);
  // Layer 2: z0 = fp8(h @ w2) ; out = bn2(A @ z0)
  gemm2_mfma<<<GGRID, 256, 0, stream>>>(h, w2s, z0);
  spmm2_kernel<<<NN / 4, 256, 0, stream>>>(z0, row_start, edges,
                                           gamma2, beta2, mean2, var2, out);
}